// Round 3
// baseline (447.397 us; speedup 1.0000x reference)
//
#include <hip/hip_runtime.h>
#include <hip/hip_bf16.h>

// Problem constants
#define Bsz 4
#define Lseq 1024
#define OBS 60
#define DM 256
#define DI 512
#define DTR 16
#define DST 16
#define NTOK (Bsz*Lseq)   // 4096
#define NCH 32            // scan chunks per sequence
#define CH  32            // steps per chunk

typedef _Float16 half8 __attribute__((ext_vector_type(8)));
typedef float floatx4 __attribute__((ext_vector_type(4)));

__device__ __forceinline__ float silu_f(float v) {
    return v * (1.f / (1.f + __expf(-v)));
}
__device__ __forceinline__ float softplus_f(float v) {
    return fmaxf(v, 0.f) + log1pf(__expf(-fabsf(v)));
}

// ---------------- weight conversion fp32 -> fp16 (x_proj padded 48->64) ----------------
#define NIN_W  (4*1024*256)
#define NX_W   (4*64*512)
#define NOUT_W (4*256*512)
__global__ __launch_bounds__(256) void convert_weights(
    const float* __restrict__ inw, const float* __restrict__ xw,
    const float* __restrict__ ow, _Float16* __restrict__ wh_in,
    _Float16* __restrict__ wh_x, _Float16* __restrict__ wh_out) {
    int idx = blockIdx.x*256 + threadIdx.x;
    if (idx < NIN_W) {
        wh_in[idx] = (_Float16)inw[idx];
    } else if (idx < NIN_W + NX_W) {
        int r = idx - NIN_W;
        int layer = r >> 15;
        int rem = r & 32767;
        int n = rem >> 9, k = rem & 511;
        wh_x[r] = (_Float16)((n < 48) ? xw[((size_t)layer*48 + n)*512 + k] : 0.f);
    } else if (idx < NIN_W + NX_W + NOUT_W) {
        int r = idx - NIN_W - NX_W;
        wh_out[r] = (_Float16)ow[r];
    }
}

// ---------------- input projection + SiLU + LN(layer0) ----------------
__global__ __launch_bounds__(256) void input_proj_ln(
    const float* __restrict__ obs, const float* __restrict__ W,
    const float* __restrict__ bias, const float* __restrict__ nw,
    const float* __restrict__ nb, float* __restrict__ x,
    _Float16* __restrict__ xn_h) {
    int t = blockIdx.x; int tid = threadIdx.x;
    __shared__ float so[OBS];
    if (tid < OBS) so[tid] = obs[t*OBS + tid];
    __syncthreads();
    float acc = bias[tid];
    const float* wr = W + tid*OBS;
    #pragma unroll
    for (int k = 0; k < OBS; ++k) acc += so[k]*wr[k];
    float v = silu_f(acc);
    x[t*DM + tid] = v;
    // layernorm
    float s = v;
    #pragma unroll
    for (int off = 32; off; off >>= 1) s += __shfl_down(s, off);
    __shared__ float ps[4];
    __shared__ float mean_s, rstd_s;
    int wid = tid >> 6, lane = tid & 63;
    if (lane == 0) ps[wid] = s;
    __syncthreads();
    if (tid == 0) mean_s = (ps[0]+ps[1]+ps[2]+ps[3]) * (1.f/DM);
    __syncthreads();
    float m = mean_s;
    float d = v - m;
    float sq = d*d;
    #pragma unroll
    for (int off = 32; off; off >>= 1) sq += __shfl_down(sq, off);
    if (lane == 0) ps[wid] = sq;
    __syncthreads();
    if (tid == 0) rstd_s = rsqrtf((ps[0]+ps[1]+ps[2]+ps[3])*(1.f/DM) + 1e-5f);
    __syncthreads();
    xn_h[t*DM + tid] = (_Float16)(d * rstd_s * nw[tid] + nb[tid]);
}

// ---------------- fp16 MFMA GEMM with fused epilogues ----------------
// C[M,N] = A[M,K] * W[N,K]^T
// EPI: 0 = fp32 C (N-guarded)            [x_proj]
//      1 = fp16 C                        [in_proj]
//      2 = resid + write x fp32 + LN -> xn_h  (needs BM=64,BN=256,WM=4,WN=1)
//      3 = resid + policy/value heads -> out   (same tile shape)
template<int BM, int BN, int WM, int WN, int EPI>
__global__ __launch_bounds__(256) void hgemm_nt(
    const _Float16* __restrict__ A, const _Float16* __restrict__ W,
    void* __restrict__ Cout, const float* __restrict__ resid,
    int M, int N, int K, int ldc,
    const float* __restrict__ e0, const float* __restrict__ e1,
    const float* __restrict__ e2, const float* __restrict__ e3,
    const float* __restrict__ e4,
    float* __restrict__ xout, _Float16* __restrict__ xnh) {
    constexpr int MFR = BM/(WM*16);
    constexpr int NFR = BN/(WN*16);
    __shared__ _Float16 As[BM*64];
    __shared__ _Float16 Bs[BN*64];
    int tid = threadIdx.x;
    int r0 = blockIdx.y*BM, c0 = blockIdx.x*BN;
    int w = tid >> 6, lane = tid & 63;
    int wr = w / WN, wc = w % WN;
    floatx4 acc[MFR][NFR];
    #pragma unroll
    for (int i = 0; i < MFR; ++i)
        #pragma unroll
        for (int j = 0; j < NFR; ++j)
            acc[i][j] = (floatx4)0.f;

    for (int k0 = 0; k0 < K; k0 += 64) {
        #pragma unroll
        for (int c = 0; c < BM/32; ++c) {
            int q = tid + 256*c;
            int row = q >> 3, cc = (q & 7)*8;
            half8 v = *(const half8*)&A[(size_t)(r0 + row)*K + k0 + cc];
            *(half8*)&As[row*64 + (cc ^ ((row & 7) << 3))] = v;
        }
        #pragma unroll
        for (int c = 0; c < BN/32; ++c) {
            int q = tid + 256*c;
            int row = q >> 3, cc = (q & 7)*8;
            half8 v = *(const half8*)&W[(size_t)(c0 + row)*K + k0 + cc];
            *(half8*)&Bs[row*64 + (cc ^ ((row & 7) << 3))] = v;
        }
        __syncthreads();
        #pragma unroll
        for (int kc = 0; kc < 2; ++kc) {
            half8 a[MFR], b[NFR];
            int col = kc*32 + (lane >> 4)*8;
            #pragma unroll
            for (int i = 0; i < MFR; ++i) {
                int row = wr*(BM/WM) + i*16 + (lane & 15);
                a[i] = *(const half8*)&As[row*64 + (col ^ ((row & 7) << 3))];
            }
            #pragma unroll
            for (int j = 0; j < NFR; ++j) {
                int row = wc*(BN/WN) + j*16 + (lane & 15);
                b[j] = *(const half8*)&Bs[row*64 + (col ^ ((row & 7) << 3))];
            }
            #pragma unroll
            for (int i = 0; i < MFR; ++i)
                #pragma unroll
                for (int j = 0; j < NFR; ++j)
                    acc[i][j] = __builtin_amdgcn_mfma_f32_16x16x32_f16(a[i], b[j], acc[i][j], 0, 0, 0);
        }
        __syncthreads();
    }
    // C/D mapping: col = lane&15, row = (lane>>4)*4 + reg
    if constexpr (EPI == 0) {
        float* C = (float*)Cout;
        #pragma unroll
        for (int i = 0; i < MFR; ++i) {
            int m0 = r0 + wr*(BM/WM) + i*16 + (lane >> 4)*4;
            #pragma unroll
            for (int j = 0; j < NFR; ++j) {
                int col = c0 + wc*(BN/WN) + j*16 + (lane & 15);
                if (col < N) {
                    #pragma unroll
                    for (int t = 0; t < 4; ++t)
                        C[(size_t)(m0 + t)*ldc + col] = acc[i][j][t];
                }
            }
        }
    } else if constexpr (EPI == 1) {
        _Float16* C = (_Float16*)Cout;
        #pragma unroll
        for (int i = 0; i < MFR; ++i) {
            int m0 = r0 + wr*(BM/WM) + i*16 + (lane >> 4)*4;
            #pragma unroll
            for (int j = 0; j < NFR; ++j) {
                int col = c0 + wc*(BN/WN) + j*16 + (lane & 15);
                #pragma unroll
                for (int t = 0; t < 4; ++t)
                    C[(size_t)(m0 + t)*ldc + col] = (_Float16)acc[i][j][t];
            }
        }
    } else {
        // BM=64, BN=256, WM=4, WN=1: MFR=1, NFR=16; wave owns full rows.
        int g = lane >> 4, ln16 = lane & 15;
        // residual add
        #pragma unroll
        for (int t = 0; t < 4; ++t) {
            int row = r0 + wr*16 + g*4 + t;
            #pragma unroll
            for (int j = 0; j < NFR; ++j)
                acc[0][j][t] += resid[(size_t)row*DM + j*16 + ln16];
        }
        if constexpr (EPI == 2) {
            #pragma unroll
            for (int t = 0; t < 4; ++t) {
                int row = r0 + wr*16 + g*4 + t;
                float s = 0.f, sq = 0.f;
                #pragma unroll
                for (int j = 0; j < NFR; ++j) {
                    float v = acc[0][j][t];
                    xout[(size_t)row*DM + j*16 + ln16] = v;
                    s += v; sq += v*v;
                }
                #pragma unroll
                for (int msk = 1; msk < 16; msk <<= 1) {
                    s += __shfl_xor(s, msk);
                    sq += __shfl_xor(sq, msk);
                }
                float mean = s * (1.f/DM);
                float rstd = rsqrtf(sq*(1.f/DM) - mean*mean + 1e-5f);
                #pragma unroll
                for (int j = 0; j < NFR; ++j) {
                    int col = j*16 + ln16;
                    float v = acc[0][j][t];
                    xnh[(size_t)row*DM + col] =
                        (_Float16)((v - mean)*rstd*e0[col] + e1[col]);
                }
            }
        } else {
            // EPI == 3: heads. e0=pw, e1=pb, e2=log_std, e3=vw, e4=vb
            float* out = xout;
            #pragma unroll
            for (int t = 0; t < 4; ++t) {
                int row = r0 + wr*16 + g*4 + t;
                float m0 = 0.f, m1 = 0.f, vv = 0.f;
                #pragma unroll
                for (int j = 0; j < NFR; ++j) {
                    int col = j*16 + ln16;
                    float v = acc[0][j][t];
                    m0 += v*e0[col]; m1 += v*e0[DM + col]; vv += v*e3[col];
                }
                #pragma unroll
                for (int msk = 1; msk < 16; msk <<= 1) {
                    m0 += __shfl_xor(m0, msk);
                    m1 += __shfl_xor(m1, msk);
                    vv += __shfl_xor(vv, msk);
                }
                if (ln16 == 0) {
                    out[row*2 + 0] = m0 + e1[0];
                    out[row*2 + 1] = m1 + e1[1];
                    out[2*NTOK + row*2 + 0] = __expf(e2[0]);
                    out[2*NTOK + row*2 + 1] = __expf(e2[1]);
                    out[4*NTOK + row] = vv + e4[0];
                }
            }
        }
    }
}

// ---------------- causal depthwise conv (width 4) + SiLU -> fp16 ----------------
__global__ __launch_bounds__(256) void conv_silu_kernel(
    const _Float16* __restrict__ xz_h, const float* __restrict__ cw,
    const float* __restrict__ cb, _Float16* __restrict__ xi_h) {
    int idx = blockIdx.x*blockDim.x + threadIdx.x;
    if (idx >= NTOK*DI) return;
    int d = idx & (DI-1); int t = idx >> 9;
    int l = t & (Lseq-1); int b = t >> 10;
    float acc = cb[d];
    #pragma unroll
    for (int k = 0; k < 4; ++k) {
        int ls = l - 3 + k;
        if (ls >= 0) acc += (float)xz_h[((size_t)(b*Lseq + ls))*(2*DI) + d] * cw[d*4 + k];
    }
    xi_h[idx] = (_Float16)silu_f(acc);
}

// ---------------- selective scan, 3-phase chunked; dt recomputed in-kernel ----------------
__global__ __launch_bounds__(256) void scan_phaseA(
    const _Float16* __restrict__ xi_h, const float* __restrict__ dbc,
    const float* __restrict__ dtw, const float* __restrict__ dtb,
    const float* __restrict__ a_log, float* __restrict__ Ap,
    float* __restrict__ He) {
    __shared__ float sdbc[CH*48];
    int blk = blockIdx.x;               // b*64 + c*2 + half
    int b = blk >> 6; int rem = blk & 63; int c = rem >> 1; int half = rem & 1;
    int d = half*256 + threadIdx.x;
    const float* src = dbc + ((size_t)(b*Lseq + c*CH))*48;
    for (int q = threadIdx.x; q < CH*48; q += 256) sdbc[q] = src[q];
    float wreg[16];
    #pragma unroll
    for (int r = 0; r < DTR; ++r) wreg[r] = dtw[d*DTR + r];
    float bias = dtb[d];
    float An[16];
    #pragma unroll
    for (int n = 0; n < 16; ++n) An[n] = -__expf(a_log[d*16 + n]);
    __syncthreads();
    float h[16] = {};
    float ap[16];
    #pragma unroll
    for (int n = 0; n < 16; ++n) ap[n] = 1.f;
    for (int s = 0; s < CH; ++s) {
        int t = b*Lseq + c*CH + s;
        float xiv = (float)xi_h[(size_t)t*DI + d];
        float dl = bias;
        #pragma unroll
        for (int r = 0; r < DTR; ++r) dl += sdbc[s*48 + r]*wreg[r];
        float dtv = softplus_f(dl);
        float u = dtv*xiv;
        #pragma unroll
        for (int n = 0; n < 16; ++n) {
            float dA = __expf(dtv*An[n]);
            h[n] = dA*h[n] + u*sdbc[s*48 + DTR + n];
            ap[n] *= dA;
        }
    }
    size_t base = ((size_t)(b*NCH + c)*16)*DI + d;
    #pragma unroll
    for (int n = 0; n < 16; ++n) { Ap[base + n*DI] = ap[n]; He[base + n*DI] = h[n]; }
}

// NOTE: h0 aliases Ap (read before write per index)
__global__ __launch_bounds__(256) void scan_phaseB(
    const float* __restrict__ Ap, const float* __restrict__ He,
    float* __restrict__ h0) {
    int g = blockIdx.x*blockDim.x + threadIdx.x;  // 32768 threads
    int b = g >> 13; int n = (g >> 9) & 15; int d = g & 511;
    float run = 0.f;
    for (int c = 0; c < NCH; ++c) {
        size_t idx = ((size_t)(b*NCH + c)*16 + n)*DI + d;
        float a = Ap[idx], e = He[idx];
        h0[idx] = run;
        run = a*run + e;
    }
}

__global__ __launch_bounds__(256) void scan_phaseC(
    const _Float16* __restrict__ xi_h, const float* __restrict__ dbc,
    const float* __restrict__ dtw, const float* __restrict__ dtb,
    const float* __restrict__ a_log, const float* __restrict__ dskip,
    const _Float16* __restrict__ xz_h, const float* __restrict__ h0,
    _Float16* __restrict__ yg_h) {
    __shared__ float sdbc[CH*48];
    int blk = blockIdx.x;
    int b = blk >> 6; int rem = blk & 63; int c = rem >> 1; int half = rem & 1;
    int d = half*256 + threadIdx.x;
    const float* src = dbc + ((size_t)(b*Lseq + c*CH))*48;
    for (int q = threadIdx.x; q < CH*48; q += 256) sdbc[q] = src[q];
    float wreg[16];
    #pragma unroll
    for (int r = 0; r < DTR; ++r) wreg[r] = dtw[d*DTR + r];
    float bias = dtb[d];
    float An[16];
    #pragma unroll
    for (int n = 0; n < 16; ++n) An[n] = -__expf(a_log[d*16 + n]);
    __syncthreads();
    float h[16];
    size_t base = ((size_t)(b*NCH + c)*16)*DI + d;
    #pragma unroll
    for (int n = 0; n < 16; ++n) h[n] = h0[base + n*DI];
    float ds = dskip[d];
    for (int s = 0; s < CH; ++s) {
        int t = b*Lseq + c*CH + s;
        float xiv = (float)xi_h[(size_t)t*DI + d];
        float dl = bias;
        #pragma unroll
        for (int r = 0; r < DTR; ++r) dl += sdbc[s*48 + r]*wreg[r];
        float dtv = softplus_f(dl);
        float u = dtv*xiv;
        float y = ds*xiv;
        #pragma unroll
        for (int n = 0; n < 16; ++n) {
            float dA = __expf(dtv*An[n]);
            h[n] = dA*h[n] + u*sdbc[s*48 + DTR + n];
            y += h[n]*sdbc[s*48 + DTR + DST + n];
        }
        float zv = (float)xz_h[(size_t)t*(2*DI) + DI + d];
        yg_h[(size_t)t*DI + d] = (_Float16)(y * silu_f(zv));
    }
}

extern "C" void kernel_launch(void* const* d_in, const int* in_sizes, int n_in,
                              void* d_out, int out_size, void* d_ws, size_t ws_size,
                              hipStream_t stream) {
    const float* obs = (const float*)d_in[0];
    const float* ipw = (const float*)d_in[1];
    const float* ipb = (const float*)d_in[2];
    const float* nw  = (const float*)d_in[3];
    const float* nb  = (const float*)d_in[4];
    const float* inw = (const float*)d_in[5];
    const float* cw  = (const float*)d_in[6];
    const float* cb  = (const float*)d_in[7];
    const float* xw  = (const float*)d_in[8];
    const float* dtw = (const float*)d_in[9];
    const float* dtb = (const float*)d_in[10];
    const float* alog= (const float*)d_in[11];
    const float* dsk = (const float*)d_in[12];
    const float* ow  = (const float*)d_in[13];
    const float* pw  = (const float*)d_in[14];
    const float* pb  = (const float*)d_in[15];
    const float* ls  = (const float*)d_in[16];
    const float* vw  = (const float*)d_in[17];
    const float* vb  = (const float*)d_in[18];
    float* out = (float*)d_out;

    float* ws = (float*)d_ws;
    float* x   = ws;                  // 1,048,576 f32
    float* dbc = x   + 1048576;       //   196,608
    float* Ap  = dbc + 196608;        // 1,048,576 (h0 aliases Ap)
    float* He  = Ap  + 1048576;       // 1,048,576
    float* h0  = Ap;                  // alias (phaseB reads before write per idx)
    _Float16* f16b  = (_Float16*)(He + 1048576);
    _Float16* xz_h  = f16b;                   // 4,194,304
    _Float16* xn_h  = xz_h  + 4194304;        // 1,048,576
    _Float16* xi_h  = xn_h  + 1048576;        // 2,097,152
    _Float16* yg_h  = xi_h  + 2097152;        // 2,097,152
    _Float16* wh_in = yg_h  + 2097152;        // 1,048,576
    _Float16* wh_x  = wh_in + 1048576;        //   131,072
    _Float16* wh_out= wh_x  + 131072;         //   524,288

    convert_weights<<<(NIN_W + NX_W + NOUT_W + 255)/256, 256, 0, stream>>>(
        inw, xw, ow, wh_in, wh_x, wh_out);
    input_proj_ln<<<NTOK, 256, 0, stream>>>(obs, ipw, ipb, nw, nb, x, xn_h);

    for (int i = 0; i < 4; ++i) {
        {   // in_proj: M=4096, N=1024, K=256 -> xz fp16
            dim3 g(1024/64, NTOK/128);
            hgemm_nt<128,64,2,2,1><<<g, 256, 0, stream>>>(
                xn_h, wh_in + (size_t)i*1024*256, xz_h, nullptr, NTOK, 1024, 256, 1024,
                nullptr, nullptr, nullptr, nullptr, nullptr, nullptr, nullptr);
        }
        conv_silu_kernel<<<(NTOK*DI)/256, 256, 0, stream>>>(xz_h, cw + i*DI*4, cb + i*DI, xi_h);
        {   // x_proj: M=4096, N=48 (padded 64), K=512 -> dbc fp32
            dim3 g(1, NTOK/64);
            hgemm_nt<64,64,2,2,0><<<g, 256, 0, stream>>>(
                xi_h, wh_x + (size_t)i*64*512, dbc, nullptr, NTOK, 48, 512, 48,
                nullptr, nullptr, nullptr, nullptr, nullptr, nullptr, nullptr);
        }
        scan_phaseA<<<Bsz*NCH*2, 256, 0, stream>>>(
            xi_h, dbc, dtw + (size_t)i*DI*DTR, dtb + i*DI,
            alog + (size_t)i*DI*DST, Ap, He);
        scan_phaseB<<<128, 256, 0, stream>>>(Ap, He, h0);
        scan_phaseC<<<Bsz*NCH*2, 256, 0, stream>>>(
            xi_h, dbc, dtw + (size_t)i*DI*DTR, dtb + i*DI,
            alog + (size_t)i*DI*DST, dsk + i*DI, xz_h, h0, yg_h);
        {   // out_proj: M=4096, N=256, K=512 + resid; fused LN (layers 0-2) / heads (layer 3)
            dim3 g(1, NTOK/64);
            if (i < 3) {
                hgemm_nt<64,256,4,1,2><<<g, 256, 0, stream>>>(
                    yg_h, wh_out + (size_t)i*256*512, nullptr, x, NTOK, 256, 512, 256,
                    nw + (i+1)*DM, nb + (i+1)*DM, nullptr, nullptr, nullptr, x, xn_h);
            } else {
                hgemm_nt<64,256,4,1,3><<<g, 256, 0, stream>>>(
                    yg_h, wh_out + (size_t)i*256*512, nullptr, x, NTOK, 256, 512, 256,
                    pw, pb, ls, vw, vb, out, nullptr);
            }
        }
    }
}

// Round 4
// 372.978 us; speedup vs baseline: 1.1995x; 1.1995x over previous
//
#include <hip/hip_runtime.h>
#include <hip/hip_bf16.h>

// Problem constants
#define Bsz 4
#define Lseq 1024
#define OBS 60
#define DM 256
#define DI 512
#define DTR 16
#define DST 16
#define NTOK (Bsz*Lseq)   // 4096
#define NCH 64            // scan chunks per sequence
#define CH  16            // steps per chunk

typedef _Float16 half8 __attribute__((ext_vector_type(8)));
typedef float floatx4 __attribute__((ext_vector_type(4)));

__device__ __forceinline__ float silu_f(float v) {
    return v * (1.f / (1.f + __expf(-v)));
}
__device__ __forceinline__ float softplus_f(float v) {
    return fmaxf(v, 0.f) + log1pf(__expf(-fabsf(v)));
}

// dA[n] = exp(dtv*An[n]); fast path when An[n] == -(n+1) (true for this model:
// A_log = log(arange(1..16)) broadcast): dA[n] = p^(n+1), p = exp(-dtv).
__device__ __forceinline__ void compute_dA(float dtv, const float* An,
                                           bool structured, float* dA) {
    if (structured) {
        float p1 = __expf(-dtv);
        float p2 = p1*p1, p4 = p2*p2, p8 = p4*p4;
        dA[0]=p1;      dA[1]=p2;      dA[2]=p2*p1;    dA[3]=p4;
        dA[4]=p4*p1;   dA[5]=p4*p2;   dA[6]=p4*dA[2]; dA[7]=p8;
        dA[8]=p8*p1;   dA[9]=p8*p2;   dA[10]=p8*dA[2];dA[11]=p8*p4;
        dA[12]=p8*dA[4];dA[13]=p8*dA[5];dA[14]=p8*dA[6];dA[15]=p8*p8;
    } else {
        #pragma unroll
        for (int n = 0; n < 16; ++n) dA[n] = __expf(dtv*An[n]);
    }
}

// ---------------- weight conversion fp32 -> fp16 (x_proj padded 48->64) ----------------
#define NIN_W  (4*1024*256)
#define NX_W   (4*64*512)
#define NOUT_W (4*256*512)
__global__ __launch_bounds__(256) void convert_weights(
    const float* __restrict__ inw, const float* __restrict__ xw,
    const float* __restrict__ ow, _Float16* __restrict__ wh_in,
    _Float16* __restrict__ wh_x, _Float16* __restrict__ wh_out) {
    int idx = blockIdx.x*256 + threadIdx.x;
    if (idx < NIN_W) {
        wh_in[idx] = (_Float16)inw[idx];
    } else if (idx < NIN_W + NX_W) {
        int r = idx - NIN_W;
        int layer = r >> 15;
        int rem = r & 32767;
        int n = rem >> 9, k = rem & 511;
        wh_x[r] = (_Float16)((n < 48) ? xw[((size_t)layer*48 + n)*512 + k] : 0.f);
    } else if (idx < NIN_W + NX_W + NOUT_W) {
        int r = idx - NIN_W - NX_W;
        wh_out[r] = (_Float16)ow[r];
    }
}

// ---------------- input projection + SiLU + LN(layer0) ----------------
__global__ __launch_bounds__(256) void input_proj_ln(
    const float* __restrict__ obs, const float* __restrict__ W,
    const float* __restrict__ bias, const float* __restrict__ nw,
    const float* __restrict__ nb, float* __restrict__ x,
    _Float16* __restrict__ xn_h) {
    int t = blockIdx.x; int tid = threadIdx.x;
    __shared__ float so[OBS];
    if (tid < OBS) so[tid] = obs[t*OBS + tid];
    __syncthreads();
    float acc = bias[tid];
    const float* wr = W + tid*OBS;
    #pragma unroll
    for (int k = 0; k < OBS; ++k) acc += so[k]*wr[k];
    float v = silu_f(acc);
    x[t*DM + tid] = v;
    float s = v;
    #pragma unroll
    for (int off = 32; off; off >>= 1) s += __shfl_down(s, off);
    __shared__ float ps[4];
    __shared__ float mean_s, rstd_s;
    int wid = tid >> 6, lane = tid & 63;
    if (lane == 0) ps[wid] = s;
    __syncthreads();
    if (tid == 0) mean_s = (ps[0]+ps[1]+ps[2]+ps[3]) * (1.f/DM);
    __syncthreads();
    float m = mean_s;
    float d = v - m;
    float sq = d*d;
    #pragma unroll
    for (int off = 32; off; off >>= 1) sq += __shfl_down(sq, off);
    if (lane == 0) ps[wid] = sq;
    __syncthreads();
    if (tid == 0) rstd_s = rsqrtf((ps[0]+ps[1]+ps[2]+ps[3])*(1.f/DM) + 1e-5f);
    __syncthreads();
    xn_h[t*DM + tid] = (_Float16)(d * rstd_s * nw[tid] + nb[tid]);
}

// ---------------- fp16 MFMA GEMM with fused epilogues ----------------
// EPI: 0 = fp32 C (N-guarded)  1 = fp16 C
//      2 = resid + x fp32 + LN -> xn_h (BM=64,BN=256,WM=4,WN=1)
//      3 = resid + policy/value heads -> out (same tile shape)
template<int BM, int BN, int WM, int WN, int EPI>
__global__ __launch_bounds__(256) void hgemm_nt(
    const _Float16* __restrict__ A, const _Float16* __restrict__ W,
    void* __restrict__ Cout, const float* __restrict__ resid,
    int M, int N, int K, int ldc,
    const float* __restrict__ e0, const float* __restrict__ e1,
    const float* __restrict__ e2, const float* __restrict__ e3,
    const float* __restrict__ e4,
    float* __restrict__ xout, _Float16* __restrict__ xnh) {
    constexpr int MFR = BM/(WM*16);
    constexpr int NFR = BN/(WN*16);
    __shared__ _Float16 As[BM*64];
    __shared__ _Float16 Bs[BN*64];
    int tid = threadIdx.x;
    int r0 = blockIdx.y*BM, c0 = blockIdx.x*BN;
    int w = tid >> 6, lane = tid & 63;
    int wr = w / WN, wc = w % WN;
    floatx4 acc[MFR][NFR];
    #pragma unroll
    for (int i = 0; i < MFR; ++i)
        #pragma unroll
        for (int j = 0; j < NFR; ++j)
            acc[i][j] = (floatx4)0.f;

    for (int k0 = 0; k0 < K; k0 += 64) {
        #pragma unroll
        for (int c = 0; c < BM/32; ++c) {
            int q = tid + 256*c;
            int row = q >> 3, cc = (q & 7)*8;
            half8 v = *(const half8*)&A[(size_t)(r0 + row)*K + k0 + cc];
            *(half8*)&As[row*64 + (cc ^ ((row & 7) << 3))] = v;
        }
        #pragma unroll
        for (int c = 0; c < BN/32; ++c) {
            int q = tid + 256*c;
            int row = q >> 3, cc = (q & 7)*8;
            half8 v = *(const half8*)&W[(size_t)(c0 + row)*K + k0 + cc];
            *(half8*)&Bs[row*64 + (cc ^ ((row & 7) << 3))] = v;
        }
        __syncthreads();
        #pragma unroll
        for (int kc = 0; kc < 2; ++kc) {
            half8 a[MFR], b[NFR];
            int col = kc*32 + (lane >> 4)*8;
            #pragma unroll
            for (int i = 0; i < MFR; ++i) {
                int row = wr*(BM/WM) + i*16 + (lane & 15);
                a[i] = *(const half8*)&As[row*64 + (col ^ ((row & 7) << 3))];
            }
            #pragma unroll
            for (int j = 0; j < NFR; ++j) {
                int row = wc*(BN/WN) + j*16 + (lane & 15);
                b[j] = *(const half8*)&Bs[row*64 + (col ^ ((row & 7) << 3))];
            }
            #pragma unroll
            for (int i = 0; i < MFR; ++i)
                #pragma unroll
                for (int j = 0; j < NFR; ++j)
                    acc[i][j] = __builtin_amdgcn_mfma_f32_16x16x32_f16(a[i], b[j], acc[i][j], 0, 0, 0);
        }
        __syncthreads();
    }
    // C/D mapping: col = lane&15, row = (lane>>4)*4 + reg
    if constexpr (EPI == 0) {
        float* C = (float*)Cout;
        #pragma unroll
        for (int i = 0; i < MFR; ++i) {
            int m0 = r0 + wr*(BM/WM) + i*16 + (lane >> 4)*4;
            #pragma unroll
            for (int j = 0; j < NFR; ++j) {
                int col = c0 + wc*(BN/WN) + j*16 + (lane & 15);
                if (col < N) {
                    #pragma unroll
                    for (int t = 0; t < 4; ++t)
                        C[(size_t)(m0 + t)*ldc + col] = acc[i][j][t];
                }
            }
        }
    } else if constexpr (EPI == 1) {
        _Float16* C = (_Float16*)Cout;
        #pragma unroll
        for (int i = 0; i < MFR; ++i) {
            int m0 = r0 + wr*(BM/WM) + i*16 + (lane >> 4)*4;
            #pragma unroll
            for (int j = 0; j < NFR; ++j) {
                int col = c0 + wc*(BN/WN) + j*16 + (lane & 15);
                #pragma unroll
                for (int t = 0; t < 4; ++t)
                    C[(size_t)(m0 + t)*ldc + col] = (_Float16)acc[i][j][t];
            }
        }
    } else {
        int g = lane >> 4, ln16 = lane & 15;
        #pragma unroll
        for (int t = 0; t < 4; ++t) {
            int row = r0 + wr*16 + g*4 + t;
            #pragma unroll
            for (int j = 0; j < NFR; ++j)
                acc[0][j][t] += resid[(size_t)row*DM + j*16 + ln16];
        }
        if constexpr (EPI == 2) {
            #pragma unroll
            for (int t = 0; t < 4; ++t) {
                int row = r0 + wr*16 + g*4 + t;
                float s = 0.f, sq = 0.f;
                #pragma unroll
                for (int j = 0; j < NFR; ++j) {
                    float v = acc[0][j][t];
                    xout[(size_t)row*DM + j*16 + ln16] = v;
                    s += v; sq += v*v;
                }
                #pragma unroll
                for (int msk = 1; msk < 16; msk <<= 1) {
                    s += __shfl_xor(s, msk);
                    sq += __shfl_xor(sq, msk);
                }
                float mean = s * (1.f/DM);
                float rstd = rsqrtf(sq*(1.f/DM) - mean*mean + 1e-5f);
                #pragma unroll
                for (int j = 0; j < NFR; ++j) {
                    int col = j*16 + ln16;
                    float v = acc[0][j][t];
                    xnh[(size_t)row*DM + col] =
                        (_Float16)((v - mean)*rstd*e0[col] + e1[col]);
                }
            }
        } else {
            float* out = xout;
            #pragma unroll
            for (int t = 0; t < 4; ++t) {
                int row = r0 + wr*16 + g*4 + t;
                float m0 = 0.f, m1 = 0.f, vv = 0.f;
                #pragma unroll
                for (int j = 0; j < NFR; ++j) {
                    int col = j*16 + ln16;
                    float v = acc[0][j][t];
                    m0 += v*e0[col]; m1 += v*e0[DM + col]; vv += v*e3[col];
                }
                #pragma unroll
                for (int msk = 1; msk < 16; msk <<= 1) {
                    m0 += __shfl_xor(m0, msk);
                    m1 += __shfl_xor(m1, msk);
                    vv += __shfl_xor(vv, msk);
                }
                if (ln16 == 0) {
                    out[row*2 + 0] = m0 + e1[0];
                    out[row*2 + 1] = m1 + e1[1];
                    out[2*NTOK + row*2 + 0] = __expf(e2[0]);
                    out[2*NTOK + row*2 + 1] = __expf(e2[1]);
                    out[4*NTOK + row] = vv + e4[0];
                }
            }
        }
    }
}

// ---------------- causal depthwise conv (width 4) + SiLU -> fp16 ----------------
__global__ __launch_bounds__(256) void conv_silu_kernel(
    const _Float16* __restrict__ xz_h, const float* __restrict__ cw,
    const float* __restrict__ cb, _Float16* __restrict__ xi_h) {
    int idx = blockIdx.x*blockDim.x + threadIdx.x;
    if (idx >= NTOK*DI) return;
    int d = idx & (DI-1); int t = idx >> 9;
    int l = t & (Lseq-1); int b = t >> 10;
    float acc = cb[d];
    #pragma unroll
    for (int k = 0; k < 4; ++k) {
        int ls = l - 3 + k;
        if (ls >= 0) acc += (float)xz_h[((size_t)(b*Lseq + ls))*(2*DI) + d] * cw[d*4 + k];
    }
    xi_h[idx] = (_Float16)silu_f(acc);
}

// ---------------- selective scan, 3-phase chunked; dt recomputed in-kernel ----------------
__global__ __launch_bounds__(256) void scan_phaseA(
    const _Float16* __restrict__ xi_h, const float* __restrict__ dbc,
    const float* __restrict__ dtw, const float* __restrict__ dtb,
    const float* __restrict__ a_log, float* __restrict__ Ap,
    float* __restrict__ He) {
    __shared__ float sdbc[CH*48];
    int blk = blockIdx.x;               // b*(2*NCH) + c*2 + half
    int b = blk >> 7; int rem = blk & 127; int c = rem >> 1; int half = rem & 1;
    int d = half*256 + threadIdx.x;
    const float* src = dbc + ((size_t)(b*Lseq + c*CH))*48;
    for (int q = threadIdx.x; q < CH*48; q += 256) sdbc[q] = src[q];
    float wreg[16];
    #pragma unroll
    for (int r = 0; r < DTR; ++r) wreg[r] = dtw[d*DTR + r];
    float bias = dtb[d];
    float An[16];
    bool structured = true;
    #pragma unroll
    for (int n = 0; n < 16; ++n) {
        An[n] = -__expf(a_log[d*16 + n]);
        structured = structured && (fabsf(An[n] + (float)(n+1)) < 1e-4f*(n+1));
    }
    __syncthreads();
    float h[16] = {};
    float ap[16];
    #pragma unroll
    for (int n = 0; n < 16; ++n) ap[n] = 1.f;
    for (int s = 0; s < CH; ++s) {
        int t = b*Lseq + c*CH + s;
        float xiv = (float)xi_h[(size_t)t*DI + d];
        float dl = bias;
        #pragma unroll
        for (int r = 0; r < DTR; ++r) dl += sdbc[s*48 + r]*wreg[r];
        float dtv = softplus_f(dl);
        float u = dtv*xiv;
        float dA[16];
        compute_dA(dtv, An, structured, dA);
        #pragma unroll
        for (int n = 0; n < 16; ++n) {
            h[n] = dA[n]*h[n] + u*sdbc[s*48 + DTR + n];
            ap[n] *= dA[n];
        }
    }
    size_t base = ((size_t)(b*NCH + c)*16)*DI + d;
    #pragma unroll
    for (int n = 0; n < 16; ++n) { Ap[base + n*DI] = ap[n]; He[base + n*DI] = h[n]; }
}

// NOTE: h0 aliases Ap (read before write per index)
__global__ __launch_bounds__(256) void scan_phaseB(
    const float* __restrict__ Ap, const float* __restrict__ He,
    float* __restrict__ h0) {
    int g = blockIdx.x*blockDim.x + threadIdx.x;  // 32768 threads
    int b = g >> 13; int n = (g >> 9) & 15; int d = g & 511;
    float run = 0.f;
    for (int c = 0; c < NCH; ++c) {
        size_t idx = ((size_t)(b*NCH + c)*16 + n)*DI + d;
        float a = Ap[idx], e = He[idx];
        h0[idx] = run;
        run = a*run + e;
    }
}

__global__ __launch_bounds__(256) void scan_phaseC(
    const _Float16* __restrict__ xi_h, const float* __restrict__ dbc,
    const float* __restrict__ dtw, const float* __restrict__ dtb,
    const float* __restrict__ a_log, const float* __restrict__ dskip,
    const _Float16* __restrict__ xz_h, const float* __restrict__ h0,
    _Float16* __restrict__ yg_h) {
    __shared__ float sdbc[CH*48];
    int blk = blockIdx.x;
    int b = blk >> 7; int rem = blk & 127; int c = rem >> 1; int half = rem & 1;
    int d = half*256 + threadIdx.x;
    const float* src = dbc + ((size_t)(b*Lseq + c*CH))*48;
    for (int q = threadIdx.x; q < CH*48; q += 256) sdbc[q] = src[q];
    float wreg[16];
    #pragma unroll
    for (int r = 0; r < DTR; ++r) wreg[r] = dtw[d*DTR + r];
    float bias = dtb[d];
    float An[16];
    bool structured = true;
    #pragma unroll
    for (int n = 0; n < 16; ++n) {
        An[n] = -__expf(a_log[d*16 + n]);
        structured = structured && (fabsf(An[n] + (float)(n+1)) < 1e-4f*(n+1));
    }
    __syncthreads();
    float h[16];
    size_t base = ((size_t)(b*NCH + c)*16)*DI + d;
    #pragma unroll
    for (int n = 0; n < 16; ++n) h[n] = h0[base + n*DI];
    float ds = dskip[d];
    for (int s = 0; s < CH; ++s) {
        int t = b*Lseq + c*CH + s;
        float xiv = (float)xi_h[(size_t)t*DI + d];
        float dl = bias;
        #pragma unroll
        for (int r = 0; r < DTR; ++r) dl += sdbc[s*48 + r]*wreg[r];
        float dtv = softplus_f(dl);
        float u = dtv*xiv;
        float dA[16];
        compute_dA(dtv, An, structured, dA);
        float y = ds*xiv;
        #pragma unroll
        for (int n = 0; n < 16; ++n) {
            h[n] = dA[n]*h[n] + u*sdbc[s*48 + DTR + n];
            y += h[n]*sdbc[s*48 + DTR + DST + n];
        }
        float zv = (float)xz_h[(size_t)t*(2*DI) + DI + d];
        yg_h[(size_t)t*DI + d] = (_Float16)(y * silu_f(zv));
    }
}

extern "C" void kernel_launch(void* const* d_in, const int* in_sizes, int n_in,
                              void* d_out, int out_size, void* d_ws, size_t ws_size,
                              hipStream_t stream) {
    const float* obs = (const float*)d_in[0];
    const float* ipw = (const float*)d_in[1];
    const float* ipb = (const float*)d_in[2];
    const float* nw  = (const float*)d_in[3];
    const float* nb  = (const float*)d_in[4];
    const float* inw = (const float*)d_in[5];
    const float* cw  = (const float*)d_in[6];
    const float* cb  = (const float*)d_in[7];
    const float* xw  = (const float*)d_in[8];
    const float* dtw = (const float*)d_in[9];
    const float* dtb = (const float*)d_in[10];
    const float* alog= (const float*)d_in[11];
    const float* dsk = (const float*)d_in[12];
    const float* ow  = (const float*)d_in[13];
    const float* pw  = (const float*)d_in[14];
    const float* pb  = (const float*)d_in[15];
    const float* ls  = (const float*)d_in[16];
    const float* vw  = (const float*)d_in[17];
    const float* vb  = (const float*)d_in[18];
    float* out = (float*)d_out;

    float* ws = (float*)d_ws;
    float* x   = ws;                  // 1,048,576 f32
    float* dbc = x   + 1048576;       //   196,608
    float* Ap  = dbc + 196608;        // 2,097,152 (h0 aliases Ap)
    float* He  = Ap  + 2097152;       // 2,097,152
    float* h0  = Ap;                  // alias (phaseB reads before write per idx)
    _Float16* f16b  = (_Float16*)(He + 2097152);
    _Float16* xz_h  = f16b;                   // 4,194,304
    _Float16* xn_h  = xz_h  + 4194304;        // 1,048,576
    _Float16* xi_h  = xn_h  + 1048576;        // 2,097,152
    _Float16* yg_h  = xi_h  + 2097152;        // 2,097,152
    _Float16* wh_in = yg_h  + 2097152;        // 1,048,576
    _Float16* wh_x  = wh_in + 1048576;        //   131,072
    _Float16* wh_out= wh_x  + 131072;         //   524,288

    convert_weights<<<(NIN_W + NX_W + NOUT_W + 255)/256, 256, 0, stream>>>(
        inw, xw, ow, wh_in, wh_x, wh_out);
    input_proj_ln<<<NTOK, 256, 0, stream>>>(obs, ipw, ipb, nw, nb, x, xn_h);

    for (int i = 0; i < 4; ++i) {
        {   // in_proj: M=4096, N=1024, K=256 -> xz fp16
            dim3 g(1024/64, NTOK/128);
            hgemm_nt<128,64,2,2,1><<<g, 256, 0, stream>>>(
                xn_h, wh_in + (size_t)i*1024*256, xz_h, nullptr, NTOK, 1024, 256, 1024,
                nullptr, nullptr, nullptr, nullptr, nullptr, nullptr, nullptr);
        }
        conv_silu_kernel<<<(NTOK*DI)/256, 256, 0, stream>>>(xz_h, cw + i*DI*4, cb + i*DI, xi_h);
        {   // x_proj: M=4096, N=48 (padded 64), K=512 -> dbc fp32
            dim3 g(1, NTOK/32);
            hgemm_nt<32,64,2,2,0><<<g, 256, 0, stream>>>(
                xi_h, wh_x + (size_t)i*64*512, dbc, nullptr, NTOK, 48, 512, 48,
                nullptr, nullptr, nullptr, nullptr, nullptr, nullptr, nullptr);
        }
        scan_phaseA<<<Bsz*NCH*2, 256, 0, stream>>>(
            xi_h, dbc, dtw + (size_t)i*DI*DTR, dtb + i*DI,
            alog + (size_t)i*DI*DST, Ap, He);
        scan_phaseB<<<128, 256, 0, stream>>>(Ap, He, h0);
        scan_phaseC<<<Bsz*NCH*2, 256, 0, stream>>>(
            xi_h, dbc, dtw + (size_t)i*DI*DTR, dtb + i*DI,
            alog + (size_t)i*DI*DST, dsk + i*DI, xz_h, h0, yg_h);
        {   // out_proj: M=4096, N=256, K=512 + resid; fused LN / heads
            dim3 g(1, NTOK/64);
            if (i < 3) {
                hgemm_nt<64,256,4,1,2><<<g, 256, 0, stream>>>(
                    yg_h, wh_out + (size_t)i*256*512, nullptr, x, NTOK, 256, 512, 256,
                    nw + (i+1)*DM, nb + (i+1)*DM, nullptr, nullptr, nullptr, x, xn_h);
            } else {
                hgemm_nt<64,256,4,1,3><<<g, 256, 0, stream>>>(
                    yg_h, wh_out + (size_t)i*256*512, nullptr, x, NTOK, 256, 512, 256,
                    pw, pb, ls, vw, vb, out, nullptr);
            }
        }
    }
}

// Round 6
// 336.482 us; speedup vs baseline: 1.3296x; 1.1085x over previous
//
#include <hip/hip_runtime.h>
#include <hip/hip_bf16.h>

// Problem constants
#define Bsz 4
#define Lseq 1024
#define OBS 60
#define DM 256
#define DI 512
#define DTR 16
#define DST 16
#define NTOK (Bsz*Lseq)   // 4096
#define NCH 64            // scan chunks per sequence
#define CH  16            // steps per chunk

typedef _Float16 half8 __attribute__((ext_vector_type(8)));
typedef float floatx4 __attribute__((ext_vector_type(4)));

__device__ __forceinline__ float silu_f(float v) {
    return v * (1.f / (1.f + __expf(-v)));
}
__device__ __forceinline__ float softplus_f(float v) {
    return fmaxf(v, 0.f) + log1pf(__expf(-fabsf(v)));
}

// dA[n] = exp(dtv*An[n]); fast path when An[n] == -(n+1) (true for this model:
// A_log = log(arange(1..16)) broadcast): dA[n] = p^(n+1), p = exp(-dtv).
__device__ __forceinline__ void compute_dA(float dtv, const float* An,
                                           bool structured, float* dA) {
    if (structured) {
        float p1 = __expf(-dtv);
        float p2 = p1*p1, p4 = p2*p2, p8 = p4*p4;
        dA[0]=p1;      dA[1]=p2;      dA[2]=p2*p1;    dA[3]=p4;
        dA[4]=p4*p1;   dA[5]=p4*p2;   dA[6]=p4*dA[2]; dA[7]=p8;
        dA[8]=p8*p1;   dA[9]=p8*p2;   dA[10]=p8*dA[2];dA[11]=p8*p4;
        dA[12]=p8*dA[4];dA[13]=p8*dA[5];dA[14]=p8*dA[6];dA[15]=p8*p8;
    } else {
        #pragma unroll
        for (int n = 0; n < 16; ++n) dA[n] = __expf(dtv*An[n]);
    }
}

// ---------------- weight conversion fp32 -> fp16 ----------------
// x_proj padded 48->64; conv weights transposed to [layer][k][d] fp16.
#define NIN_W  (4*1024*256)
#define NX_W   (4*64*512)
#define NOUT_W (4*256*512)
#define NCWT   (4*4*512)
__global__ __launch_bounds__(256) void convert_weights(
    const float* __restrict__ inw, const float* __restrict__ xw,
    const float* __restrict__ ow, const float* __restrict__ cw,
    _Float16* __restrict__ wh_in, _Float16* __restrict__ wh_x,
    _Float16* __restrict__ wh_out, _Float16* __restrict__ cwT) {
    int idx = blockIdx.x*256 + threadIdx.x;
    if (idx < NIN_W) {
        wh_in[idx] = (_Float16)inw[idx];
    } else if (idx < NIN_W + NX_W) {
        int r = idx - NIN_W;
        int layer = r >> 15;
        int rem = r & 32767;
        int n = rem >> 9, k = rem & 511;
        wh_x[r] = (_Float16)((n < 48) ? xw[((size_t)layer*48 + n)*512 + k] : 0.f);
    } else if (idx < NIN_W + NX_W + NOUT_W) {
        int r = idx - NIN_W - NX_W;
        wh_out[r] = (_Float16)ow[r];
    } else if (idx < NIN_W + NX_W + NOUT_W + NCWT) {
        int r = idx - NIN_W - NX_W - NOUT_W;
        int layer = r >> 11;
        int rem = r & 2047;
        int k = rem >> 9, d = rem & 511;
        cwT[r] = (_Float16)cw[layer*2048 + d*4 + k];
    }
}

// ---------------- input projection + SiLU + LN(layer0) ----------------
__global__ __launch_bounds__(256) void input_proj_ln(
    const float* __restrict__ obs, const float* __restrict__ W,
    const float* __restrict__ bias, const float* __restrict__ nw,
    const float* __restrict__ nb, float* __restrict__ x,
    _Float16* __restrict__ xn_h) {
    int t = blockIdx.x; int tid = threadIdx.x;
    __shared__ float so[OBS];
    if (tid < OBS) so[tid] = obs[t*OBS + tid];
    __syncthreads();
    float acc = bias[tid];
    const float* wr = W + tid*OBS;
    #pragma unroll
    for (int k = 0; k < OBS; ++k) acc += so[k]*wr[k];
    float v = silu_f(acc);
    x[t*DM + tid] = v;
    float s = v;
    #pragma unroll
    for (int off = 32; off; off >>= 1) s += __shfl_down(s, off);
    __shared__ float ps[4];
    __shared__ float mean_s, rstd_s;
    int wid = tid >> 6, lane = tid & 63;
    if (lane == 0) ps[wid] = s;
    __syncthreads();
    if (tid == 0) mean_s = (ps[0]+ps[1]+ps[2]+ps[3]) * (1.f/DM);
    __syncthreads();
    float m = mean_s;
    float d = v - m;
    float sq = d*d;
    #pragma unroll
    for (int off = 32; off; off >>= 1) sq += __shfl_down(sq, off);
    if (lane == 0) ps[wid] = sq;
    __syncthreads();
    if (tid == 0) rstd_s = rsqrtf((ps[0]+ps[1]+ps[2]+ps[3])*(1.f/DM) + 1e-5f);
    __syncthreads();
    xn_h[t*DM + tid] = (_Float16)(d * rstd_s * nw[tid] + nb[tid]);
}

// ---------------- fp16 MFMA GEMM with fused epilogues ----------------
// EPI: 1 = fp16 C
//      2 = resid + x fp32 + LN -> xn_h (BM=64,BN=256,WM=4,WN=1)
//      3 = resid + policy/value heads -> out (same tile shape)
template<int BM, int BN, int WM, int WN, int EPI>
__global__ __launch_bounds__(256) void hgemm_nt(
    const _Float16* __restrict__ A, const _Float16* __restrict__ W,
    void* __restrict__ Cout, const float* __restrict__ resid,
    int M, int N, int K, int ldc,
    const float* __restrict__ e0, const float* __restrict__ e1,
    const float* __restrict__ e2, const float* __restrict__ e3,
    const float* __restrict__ e4,
    float* __restrict__ xout, _Float16* __restrict__ xnh) {
    constexpr int MFR = BM/(WM*16);
    constexpr int NFR = BN/(WN*16);
    __shared__ _Float16 As[BM*64];
    __shared__ _Float16 Bs[BN*64];
    int tid = threadIdx.x;
    int r0 = blockIdx.y*BM, c0 = blockIdx.x*BN;
    int w = tid >> 6, lane = tid & 63;
    int wr = w / WN, wc = w % WN;
    floatx4 acc[MFR][NFR];
    #pragma unroll
    for (int i = 0; i < MFR; ++i)
        #pragma unroll
        for (int j = 0; j < NFR; ++j)
            acc[i][j] = (floatx4)0.f;

    for (int k0 = 0; k0 < K; k0 += 64) {
        #pragma unroll
        for (int c = 0; c < BM/32; ++c) {
            int q = tid + 256*c;
            int row = q >> 3, cc = (q & 7)*8;
            half8 v = *(const half8*)&A[(size_t)(r0 + row)*K + k0 + cc];
            *(half8*)&As[row*64 + (cc ^ ((row & 7) << 3))] = v;
        }
        #pragma unroll
        for (int c = 0; c < BN/32; ++c) {
            int q = tid + 256*c;
            int row = q >> 3, cc = (q & 7)*8;
            half8 v = *(const half8*)&W[(size_t)(c0 + row)*K + k0 + cc];
            *(half8*)&Bs[row*64 + (cc ^ ((row & 7) << 3))] = v;
        }
        __syncthreads();
        #pragma unroll
        for (int kc = 0; kc < 2; ++kc) {
            half8 a[MFR], b[NFR];
            int col = kc*32 + (lane >> 4)*8;
            #pragma unroll
            for (int i = 0; i < MFR; ++i) {
                int row = wr*(BM/WM) + i*16 + (lane & 15);
                a[i] = *(const half8*)&As[row*64 + (col ^ ((row & 7) << 3))];
            }
            #pragma unroll
            for (int j = 0; j < NFR; ++j) {
                int row = wc*(BN/WN) + j*16 + (lane & 15);
                b[j] = *(const half8*)&Bs[row*64 + (col ^ ((row & 7) << 3))];
            }
            #pragma unroll
            for (int i = 0; i < MFR; ++i)
                #pragma unroll
                for (int j = 0; j < NFR; ++j)
                    acc[i][j] = __builtin_amdgcn_mfma_f32_16x16x32_f16(a[i], b[j], acc[i][j], 0, 0, 0);
        }
        __syncthreads();
    }
    // C/D mapping: col = lane&15, row = (lane>>4)*4 + reg
    if constexpr (EPI == 1) {
        _Float16* C = (_Float16*)Cout;
        #pragma unroll
        for (int i = 0; i < MFR; ++i) {
            int m0 = r0 + wr*(BM/WM) + i*16 + (lane >> 4)*4;
            #pragma unroll
            for (int j = 0; j < NFR; ++j) {
                int col = c0 + wc*(BN/WN) + j*16 + (lane & 15);
                #pragma unroll
                for (int t = 0; t < 4; ++t)
                    C[(size_t)(m0 + t)*ldc + col] = (_Float16)acc[i][j][t];
            }
        }
    } else if constexpr (EPI == 2 || EPI == 3) {
        int g = lane >> 4, ln16 = lane & 15;
        #pragma unroll
        for (int t = 0; t < 4; ++t) {
            int row = r0 + wr*16 + g*4 + t;
            #pragma unroll
            for (int j = 0; j < NFR; ++j)
                acc[0][j][t] += resid[(size_t)row*DM + j*16 + ln16];
        }
        if constexpr (EPI == 2) {
            #pragma unroll
            for (int t = 0; t < 4; ++t) {
                int row = r0 + wr*16 + g*4 + t;
                float s = 0.f, sq = 0.f;
                #pragma unroll
                for (int j = 0; j < NFR; ++j) {
                    float v = acc[0][j][t];
                    xout[(size_t)row*DM + j*16 + ln16] = v;
                    s += v; sq += v*v;
                }
                #pragma unroll
                for (int msk = 1; msk < 16; msk <<= 1) {
                    s += __shfl_xor(s, msk);
                    sq += __shfl_xor(sq, msk);
                }
                float mean = s * (1.f/DM);
                float rstd = rsqrtf(sq*(1.f/DM) - mean*mean + 1e-5f);
                #pragma unroll
                for (int j = 0; j < NFR; ++j) {
                    int col = j*16 + ln16;
                    float v = acc[0][j][t];
                    xnh[(size_t)row*DM + col] =
                        (_Float16)((v - mean)*rstd*e0[col] + e1[col]);
                }
            }
        } else {
            float* out = xout;
            #pragma unroll
            for (int t = 0; t < 4; ++t) {
                int row = r0 + wr*16 + g*4 + t;
                float m0 = 0.f, m1 = 0.f, vv = 0.f;
                #pragma unroll
                for (int j = 0; j < NFR; ++j) {
                    int col = j*16 + ln16;
                    float v = acc[0][j][t];
                    m0 += v*e0[col]; m1 += v*e0[DM + col]; vv += v*e3[col];
                }
                #pragma unroll
                for (int msk = 1; msk < 16; msk <<= 1) {
                    m0 += __shfl_xor(m0, msk);
                    m1 += __shfl_xor(m1, msk);
                    vv += __shfl_xor(vv, msk);
                }
                if (ln16 == 0) {
                    out[row*2 + 0] = m0 + e1[0];
                    out[row*2 + 1] = m1 + e1[1];
                    out[2*NTOK + row*2 + 0] = __expf(e2[0]);
                    out[2*NTOK + row*2 + 1] = __expf(e2[1]);
                    out[4*NTOK + row] = vv + e4[0];
                }
            }
        }
    }
}

// ---------------- x_proj GEMM with conv+SiLU fused into A-staging ----------------
// dbc[t][48] = silu(conv(xz))[t] @ Wx^T.  BM=32, BN=64(48 valid), BK=64, 4 waves 2x2.
__global__ __launch_bounds__(256) void xproj_conv_gemm(
    const _Float16* __restrict__ xz_h, const _Float16* __restrict__ Wx,
    const _Float16* __restrict__ cwT, const float* __restrict__ cb,
    float* __restrict__ dbc) {
    __shared__ _Float16 As[32*64];
    __shared__ _Float16 Bs[64*64];
    int tid = threadIdx.x;
    int r0 = blockIdx.x*32;
    int w = tid >> 6, lane = tid & 63;
    int wr = w >> 1, wc = w & 1;
    floatx4 acc[2];
    acc[0] = (floatx4)0.f; acc[1] = (floatx4)0.f;
    for (int k0 = 0; k0 < 512; k0 += 64) {
        {   // A-stage: conv + SiLU on the fly
            int row = tid >> 3, e8 = tid & 7;
            int d = k0 + e8*8;
            int t = r0 + row, l = t & (Lseq-1);
            half8 zero8;
            zero8 = (half8)((_Float16)0.f);
            half8 v0 = (l >= 3) ? *(const half8*)&xz_h[(size_t)(t-3)*1024 + d] : zero8;
            half8 v1 = (l >= 2) ? *(const half8*)&xz_h[(size_t)(t-2)*1024 + d] : zero8;
            half8 v2 = (l >= 1) ? *(const half8*)&xz_h[(size_t)(t-1)*1024 + d] : zero8;
            half8 v3 = *(const half8*)&xz_h[(size_t)t*1024 + d];
            half8 c0 = *(const half8*)&cwT[0*512 + d];
            half8 c1 = *(const half8*)&cwT[1*512 + d];
            half8 c2 = *(const half8*)&cwT[2*512 + d];
            half8 c3 = *(const half8*)&cwT[3*512 + d];
            half8 o;
            #pragma unroll
            for (int e = 0; e < 8; ++e) {
                float a = cb[d + e];
                a += (float)v0[e]*(float)c0[e];
                a += (float)v1[e]*(float)c1[e];
                a += (float)v2[e]*(float)c2[e];
                a += (float)v3[e]*(float)c3[e];
                o[e] = (_Float16)silu_f(a);
            }
            *(half8*)&As[row*64 + ((e8*8) ^ ((row & 7) << 3))] = o;
        }
        #pragma unroll
        for (int c = 0; c < 2; ++c) {   // B-stage
            int q = tid + 256*c;
            int row = q >> 3, cc = (q & 7)*8;
            half8 vv = *(const half8*)&Wx[(size_t)row*512 + k0 + cc];
            *(half8*)&Bs[row*64 + (cc ^ ((row & 7) << 3))] = vv;
        }
        __syncthreads();
        #pragma unroll
        for (int kc = 0; kc < 2; ++kc) {
            int col = kc*32 + (lane >> 4)*8;
            int arow = wr*16 + (lane & 15);
            half8 a = *(const half8*)&As[arow*64 + (col ^ ((arow & 7) << 3))];
            #pragma unroll
            for (int j = 0; j < 2; ++j) {
                int brow = wc*32 + j*16 + (lane & 15);
                half8 b = *(const half8*)&Bs[brow*64 + (col ^ ((brow & 7) << 3))];
                acc[j] = __builtin_amdgcn_mfma_f32_16x16x32_f16(a, b, acc[j], 0, 0, 0);
            }
        }
        __syncthreads();
    }
    int m0 = r0 + wr*16 + (lane >> 4)*4;
    #pragma unroll
    for (int j = 0; j < 2; ++j) {
        int col = wc*32 + j*16 + (lane & 15);
        if (col < 48) {
            #pragma unroll
            for (int t = 0; t < 4; ++t)
                dbc[(size_t)(m0 + t)*48 + col] = acc[j][t];
        }
    }
}

// ---------------- selective scan, 3-phase chunked ----------------
// phaseA: conv+SiLU (rolling window) + dt + local scan; stores xi_h, dt_h, summaries fp16.
__global__ __launch_bounds__(256) void scan_phaseA(
    const _Float16* __restrict__ xz_h, const float* __restrict__ dbc,
    const float* __restrict__ dtw, const float* __restrict__ dtb,
    const float* __restrict__ a_log, const float* __restrict__ cw,
    const float* __restrict__ cb,
    _Float16* __restrict__ xi_h, _Float16* __restrict__ dt_h,
    _Float16* __restrict__ Ap, _Float16* __restrict__ He) {
    __shared__ float sdbc[CH*48];
    int blk = blockIdx.x;               // b*(2*NCH) + c*2 + half
    int b = blk >> 7; int rem = blk & 127; int c = rem >> 1; int half = rem & 1;
    int d = half*256 + threadIdx.x;
    const float* src = dbc + ((size_t)(b*Lseq + c*CH))*48;
    for (int q = threadIdx.x; q < CH*48; q += 256) sdbc[q] = src[q];
    float wreg[16];
    #pragma unroll
    for (int r = 0; r < DTR; ++r) wreg[r] = dtw[d*DTR + r];
    float bias = dtb[d];
    float4 cwv = *(const float4*)&cw[d*4];
    float cbv = cb[d];
    float An[16];
    bool structured = true;
    #pragma unroll
    for (int n = 0; n < 16; ++n) {
        An[n] = -__expf(a_log[d*16 + n]);
        structured = structured && (fabsf(An[n] + (float)(n+1)) < 1e-4f*(n+1));
    }
    int l0 = c*CH; int t0 = b*Lseq + l0;
    float w0 = 0.f, w1 = 0.f, w2 = 0.f;
    if (l0 >= 3) {
        w0 = (float)xz_h[(size_t)(t0-3)*1024 + d];
        w1 = (float)xz_h[(size_t)(t0-2)*1024 + d];
        w2 = (float)xz_h[(size_t)(t0-1)*1024 + d];
    }
    __syncthreads();
    float h[16] = {};
    float ap[16];
    #pragma unroll
    for (int n = 0; n < 16; ++n) ap[n] = 1.f;
    for (int s = 0; s < CH; ++s) {
        float cur = (float)xz_h[(size_t)(t0+s)*1024 + d];
        float conv = cbv + cwv.x*w0 + cwv.y*w1 + cwv.z*w2 + cwv.w*cur;
        w0 = w1; w1 = w2; w2 = cur;
        float xiv = silu_f(conv);
        float dl = bias;
        #pragma unroll
        for (int r = 0; r < DTR; ++r) dl += sdbc[s*48 + r]*wreg[r];
        float dtv = softplus_f(dl);
        size_t ti = (size_t)(t0+s)*DI + d;
        xi_h[ti] = (_Float16)xiv;
        dt_h[ti] = (_Float16)dtv;
        float u = dtv*xiv;
        float dA[16];
        compute_dA(dtv, An, structured, dA);
        #pragma unroll
        for (int n = 0; n < 16; ++n) {
            h[n] = dA[n]*h[n] + u*sdbc[s*48 + DTR + n];
            ap[n] *= dA[n];
        }
    }
    size_t base = ((size_t)(b*NCH + c)*16)*DI + d;
    #pragma unroll
    for (int n = 0; n < 16; ++n) {
        Ap[base + n*DI] = (_Float16)ap[n];
        He[base + n*DI] = (_Float16)h[n];
    }
}

// NOTE: h0 aliases Ap (read before write per index)
__global__ __launch_bounds__(256) void scan_phaseB(
    const _Float16* __restrict__ Ap, const _Float16* __restrict__ He,
    _Float16* __restrict__ h0) {
    int g = blockIdx.x*blockDim.x + threadIdx.x;  // 32768 threads
    int b = g >> 13; int n = (g >> 9) & 15; int d = g & 511;
    float run = 0.f;
    for (int c = 0; c < NCH; ++c) {
        size_t idx = ((size_t)(b*NCH + c)*16 + n)*DI + d;
        float a = (float)Ap[idx], e = (float)He[idx];
        h0[idx] = (_Float16)run;
        run = a*run + e;
    }
}

// phaseC: loads xi_h/dt_h (no conv, no dt recompute); y + z-gate.
__global__ __launch_bounds__(256) void scan_phaseC(
    const _Float16* __restrict__ xi_h, const _Float16* __restrict__ dt_h,
    const float* __restrict__ dbc, const float* __restrict__ a_log,
    const float* __restrict__ dskip, const _Float16* __restrict__ xz_h,
    const _Float16* __restrict__ h0, _Float16* __restrict__ yg_h) {
    __shared__ float sdbc[CH*48];
    int blk = blockIdx.x;
    int b = blk >> 7; int rem = blk & 127; int c = rem >> 1; int half = rem & 1;
    int d = half*256 + threadIdx.x;
    const float* src = dbc + ((size_t)(b*Lseq + c*CH))*48;
    for (int q = threadIdx.x; q < CH*48; q += 256) sdbc[q] = src[q];
    float An[16];
    bool structured = true;
    #pragma unroll
    for (int n = 0; n < 16; ++n) {
        An[n] = -__expf(a_log[d*16 + n]);
        structured = structured && (fabsf(An[n] + (float)(n+1)) < 1e-4f*(n+1));
    }
    __syncthreads();
    int t0 = b*Lseq + c*CH;
    float h[16];
    size_t base = ((size_t)(b*NCH + c)*16)*DI + d;
    #pragma unroll
    for (int n = 0; n < 16; ++n) h[n] = (float)h0[base + n*DI];
    float ds = dskip[d];
    for (int s = 0; s < CH; ++s) {
        size_t ti = (size_t)(t0+s)*DI + d;
        float xiv = (float)xi_h[ti];
        float dtv = (float)dt_h[ti];
        float u = dtv*xiv;
        float dA[16];
        compute_dA(dtv, An, structured, dA);
        float y = ds*xiv;
        #pragma unroll
        for (int n = 0; n < 16; ++n) {
            h[n] = dA[n]*h[n] + u*sdbc[s*48 + DTR + n];
            y += h[n]*sdbc[s*48 + DTR + DST + n];
        }
        float zv = (float)xz_h[(size_t)(t0+s)*1024 + DI + d];
        yg_h[ti] = (_Float16)(y * silu_f(zv));
    }
}

extern "C" void kernel_launch(void* const* d_in, const int* in_sizes, int n_in,
                              void* d_out, int out_size, void* d_ws, size_t ws_size,
                              hipStream_t stream) {
    const float* obs = (const float*)d_in[0];
    const float* ipw = (const float*)d_in[1];
    const float* ipb = (const float*)d_in[2];
    const float* nw  = (const float*)d_in[3];
    const float* nb  = (const float*)d_in[4];
    const float* inw = (const float*)d_in[5];
    const float* cw  = (const float*)d_in[6];
    const float* cb  = (const float*)d_in[7];
    const float* xw  = (const float*)d_in[8];
    const float* dtw = (const float*)d_in[9];
    const float* dtb = (const float*)d_in[10];
    const float* alog= (const float*)d_in[11];
    const float* dsk = (const float*)d_in[12];
    const float* ow  = (const float*)d_in[13];
    const float* pw  = (const float*)d_in[14];
    const float* pb  = (const float*)d_in[15];
    const float* ls  = (const float*)d_in[16];
    const float* vw  = (const float*)d_in[17];
    const float* vb  = (const float*)d_in[18];
    float* out = (float*)d_out;

    float* ws = (float*)d_ws;
    float* x   = ws;                  // 1,048,576 f32
    float* dbc = x   + 1048576;       //   196,608 f32
    _Float16* f16b  = (_Float16*)(dbc + 196608);
    _Float16* xz_h  = f16b;                   // 4,194,304
    _Float16* xn_h  = xz_h  + 4194304;        // 1,048,576
    _Float16* xi_h  = xn_h  + 1048576;        // 2,097,152
    _Float16* dt_h  = xi_h  + 2097152;        // 2,097,152
    _Float16* yg_h  = dt_h  + 2097152;        // 2,097,152
    _Float16* Ap_h  = yg_h  + 2097152;        // 2,097,152 (h0 aliases Ap)
    _Float16* He_h  = Ap_h  + 2097152;        // 2,097,152
    _Float16* h0_h  = Ap_h;                   // alias (phaseB reads before write)
    _Float16* wh_in = He_h  + 2097152;        // 1,048,576
    _Float16* wh_x  = wh_in + 1048576;        //   131,072
    _Float16* wh_out= wh_x  + 131072;         //   524,288
    _Float16* cwT_h = wh_out+ 524288;         //     8,192

    convert_weights<<<(NIN_W + NX_W + NOUT_W + NCWT + 255)/256, 256, 0, stream>>>(
        inw, xw, ow, cw, wh_in, wh_x, wh_out, cwT_h);
    input_proj_ln<<<NTOK, 256, 0, stream>>>(obs, ipw, ipb, nw, nb, x, xn_h);

    for (int i = 0; i < 4; ++i) {
        {   // in_proj: M=4096, N=1024, K=256 -> xz fp16
            dim3 g(1024/64, NTOK/128);
            hgemm_nt<128,64,2,2,1><<<g, 256, 0, stream>>>(
                xn_h, wh_in + (size_t)i*1024*256, xz_h, nullptr, NTOK, 1024, 256, 1024,
                nullptr, nullptr, nullptr, nullptr, nullptr, nullptr, nullptr);
        }
        // x_proj with fused conv+SiLU A-staging: M=4096, N=48(64), K=512
        xproj_conv_gemm<<<NTOK/32, 256, 0, stream>>>(
            xz_h, wh_x + (size_t)i*64*512, cwT_h + i*2048, cb + i*DI, dbc);
        scan_phaseA<<<Bsz*NCH*2, 256, 0, stream>>>(
            xz_h, dbc, dtw + (size_t)i*DI*DTR, dtb + i*DI,
            alog + (size_t)i*DI*DST, cw + (size_t)i*DI*4, cb + i*DI,
            xi_h, dt_h, Ap_h, He_h);
        scan_phaseB<<<128, 256, 0, stream>>>(Ap_h, He_h, h0_h);
        scan_phaseC<<<Bsz*NCH*2, 256, 0, stream>>>(
            xi_h, dt_h, dbc, alog + (size_t)i*DI*DST,
            dsk + i*DI, xz_h, h0_h, yg_h);
        {   // out_proj: M=4096, N=256, K=512 + resid; fused LN / heads
            dim3 g(1, NTOK/64);
            if (i < 3) {
                hgemm_nt<64,256,4,1,2><<<g, 256, 0, stream>>>(
                    yg_h, wh_out + (size_t)i*256*512, nullptr, x, NTOK, 256, 512, 256,
                    nw + (i+1)*DM, nb + (i+1)*DM, nullptr, nullptr, nullptr, x, xn_h);
            } else {
                hgemm_nt<64,256,4,1,3><<<g, 256, 0, stream>>>(
                    yg_h, wh_out + (size_t)i*256*512, nullptr, x, NTOK, 256, 512, 256,
                    pw, pb, ls, vw, vb, out, nullptr);
            }
        }
    }
}